// Round 7
// baseline (73.743 us; speedup 1.0000x reference)
//
#include <hip/hip_runtime.h>

#define MAX_TRUE 128
#define MAX_CAND 256
#define NBANK 128

// anchors per (scale, anchor): ANCHOR_MASK = [[6,7,8],[3,4,5],[0,1,2]]
__device__ const float d_anch[3][3][2] = {
    {{116.f, 90.f}, {156.f, 198.f}, {373.f, 326.f}},
    {{30.f, 61.f}, {62.f, 45.f}, {59.f, 119.f}},
    {{10.f, 13.f}, {16.f, 30.f}, {33.f, 23.f}},
};

__device__ __forceinline__ float softplusf_(float x) {
    return fmaxf(x, 0.0f) + log1pf(expf(-fabsf(x)));
}
__device__ __forceinline__ float bcef_(float l, float t) {
    return softplusf_(l) - l * t;
}
__device__ __forceinline__ float sigmoidf_(float x) {
    return 1.0f / (1.0f + expf(-x));
}

// Phase 0: zero the workspace header (cnt + banks). Replaces the runtime's
// fillBufferAligned blit (which cost ~54 us/dispatch in the graph).
__global__ void zero_ws(float* __restrict__ ws_head, int nwords) {
    int i = threadIdx.x;
    for (; i < nwords; i += 256) ws_head[i] = 0.f;
}

// Phase 1: merged over all 3 scales. One thread per cell. Writes obj byte
// mask and compacts candidate boxes with their flat cell index.
__global__ void cand_kernel(const float* __restrict__ yt0, const float* __restrict__ yt1,
                            const float* __restrict__ yt2,
                            unsigned char* __restrict__ objmask,
                            float* __restrict__ cand, int* __restrict__ cnt) {
    int bid = blockIdx.x;
    const float* yt;
    int s, ridx0, cells, objofs, spb;
    if (bid < 68)       { s = 0; yt = yt0; ridx0 = bid * 256;         cells = 17328;  objofs = 0;     spb = 1083;  }
    else if (bid < 339) { s = 1; yt = yt1; ridx0 = (bid - 68) * 256;  cells = 69312;  objofs = 17328; spb = 4332;  }
    else                { s = 2; yt = yt2; ridx0 = (bid - 339) * 256; cells = 277248; objofs = 86640; spb = 17328; }
    int ridx = ridx0 + threadIdx.x;
    if (ridx >= cells) return;
    const float* src = yt + (size_t)ridx * 85;
    float obj = src[4];
    objmask[objofs + ridx] = (obj > 0.5f) ? 1 : 0;
    if (obj > 0.5f) {
        int b = ridx / spb;
        int cell = ridx - b * spb;
        int slot = s * 16 + b;
        int pos = atomicAdd(&cnt[slot], 1);
        if (pos < MAX_CAND) {
            float* d = cand + ((size_t)slot * MAX_CAND + pos) * 5;
            d[0] = src[0];
            d[1] = src[1];
            d[2] = src[2];
            d[3] = src[3];
            ((int*)d)[4] = cell;
        }
    }
}

// Phase 2: per-slot box table, SoA: corners float4 + area. Exactly 128
// entries, zero-filled beyond count (zero boxes are IoU-neutral). If
// count>128 (statistically unreachable) bitonic-sort by flat cell index
// reproduces the reference's stable first-128 selection.
__global__ void select_boxes(const float* __restrict__ cand, const int* __restrict__ cnt,
                             float4* __restrict__ boxesA, float* __restrict__ boxesT,
                             int* __restrict__ counts) {
    __shared__ int key[MAX_CAND];
    __shared__ short perm[MAX_CAND];
    int slot = blockIdx.x;
    int t = threadIdx.x;  // 256
    int c = min(cnt[slot], MAX_CAND);
    const float* cb = cand + (size_t)slot * MAX_CAND * 5;
    int src = t;
    if (c > MAX_TRUE) {
        key[t] = (t < c) ? ((const int*)cb)[t * 5 + 4] : 0x7FFFFFFF;
        perm[t] = (short)t;
        for (int k = 2; k <= MAX_CAND; k <<= 1) {
            for (int j = k >> 1; j > 0; j >>= 1) {
                __syncthreads();
                int ixj = t ^ j;
                if (ixj > t) {
                    bool asc = ((t & k) == 0);
                    int a = key[t], bk = key[ixj];
                    if ((a > bk) == asc) {
                        key[t] = bk; key[ixj] = a;
                        short p = perm[t]; perm[t] = perm[ixj]; perm[ixj] = p;
                    }
                }
            }
        }
        __syncthreads();
        src = perm[t];
    }
    if (t < MAX_TRUE) {
        float4 r;
        float ta;
        if (t < c) {
            float x = cb[src * 5 + 0], y = cb[src * 5 + 1];
            float w = cb[src * 5 + 2], h = cb[src * 5 + 3];
            r.x = x - 0.5f * w; r.y = y - 0.5f * h;
            r.z = x + 0.5f * w; r.w = y + 0.5f * h;
            ta = w * h;
        } else {
            r.x = r.y = r.z = r.w = 0.f;
            ta = 0.f;
        }
        boxesA[slot * MAX_TRUE + t] = r;
        boxesT[slot * MAX_TRUE + t] = ta;
    }
    if (t == 0) counts[slot] = min(c, MAX_TRUE);
}

// Phase 3a: losses for obj cells only. One wave per candidate, no loop.
// grid = (MAX_CAND/4, 48), block = 256 (4 waves). Atomic accumulation is
// privatized into NBANK 64-byte-separated banks to avoid same-line
// serialization.
__global__ void obj_loss_kernel(const float* __restrict__ fm0, const float* __restrict__ fm1,
                                const float* __restrict__ fm2,
                                const float* __restrict__ yt0, const float* __restrict__ yt1,
                                const float* __restrict__ yt2,
                                const float* __restrict__ cand, const int* __restrict__ cnt,
                                float* __restrict__ banks /* NBANK x 16 floats (64B apart) */) {
    int slot = blockIdx.y;
    int c = min(cnt[slot], MAX_CAND);
    if ((int)(blockIdx.x * 4) >= c) return;
    int wid = threadIdx.x >> 6, lane = threadIdx.x & 63;
    int ci = blockIdx.x * 4 + wid;
    int s = slot >> 4, b = slot & 15;
    const float* fm = (s == 0) ? fm0 : ((s == 1) ? fm1 : fm2);
    const float* yt = (s == 0) ? yt0 : ((s == 1) ? yt1 : yt2);
    int Sdim = (s == 0) ? 19 : ((s == 1) ? 38 : 76);
    int HW = Sdim * Sdim, spb = HW * 3;
    float axy = 0.f, awh = 0.f, aconf = 0.f, acls = 0.f;
    if (ci < c) {
        const float* cd = cand + ((size_t)slot * MAX_CAND + ci) * 5;
        float x = cd[0], y = cd[1], w = cd[2], h = cd[3];
        int cell = ((const int*)cd)[4];
        int hw = cell / 3, a = cell - hw * 3;
        int hh = hw / Sdim, ww = hw - hh * Sdim;
        const float* f = fm + ((size_t)(b * 255 + a * 85)) * HW + hw;
        const float* yrow = yt + ((size_t)b * spb + cell) * 85;
        // classes: lane handles k=lane, and k=64+lane for lane<16
        float cl = bcef_(f[(size_t)(5 + lane) * HW], yrow[5 + lane]);
        if (lane < 16) {
            int k2 = 64 + lane;
            cl += bcef_(f[(size_t)(5 + k2) * HW], yrow[5 + k2]);
        }
        acls = cl;
        float bscale = 2.f - w * h;
        if (lane < 5) {
            float lv = f[(size_t)lane * HW];
            if (lane == 0) axy = bscale * bcef_(lv, x * (float)Sdim - (float)ww);
            else if (lane == 1) axy = bscale * bcef_(lv, y * (float)Sdim - (float)hh);
            else if (lane == 2) {
                float tw = logf(w / d_anch[s][a][0] * 608.f);
                float d = lv - tw;
                awh = bscale * d * d;
            } else if (lane == 3) {
                float th = logf(h / d_anch[s][a][1] * 608.f);
                float d = lv - th;
                awh = bscale * d * d;
            } else {
                aconf = bcef_(lv, 1.0f);
            }
        }
    }
    #pragma unroll
    for (int o = 32; o > 0; o >>= 1) {
        axy += __shfl_down(axy, o);
        awh += __shfl_down(awh, o);
        aconf += __shfl_down(aconf, o);
        acls += __shfl_down(acls, o);
    }
    if (lane == 0) {
        int bank = (blockIdx.y * 64 + blockIdx.x) & (NBANK - 1);
        float* bp = banks + bank * 16;  // 64B-separated
        atomicAdd(&bp[0], axy);
        atomicAdd(&bp[1], awh);
        atomicAdd(&bp[2], aconf);
        atomicAdd(&bp[3], acls);
    }
}

// Phase 3b: dense conf loss for non-obj cells. 128-thread blocks.
__global__ void conf_kernel(const float* __restrict__ fm0, const float* __restrict__ fm1,
                            const float* __restrict__ fm2,
                            const unsigned char* __restrict__ objmask,
                            const float4* __restrict__ boxesA, const float* __restrict__ boxesT,
                            const int* __restrict__ counts,
                            float* __restrict__ partials) {
    __shared__ float4 sA[MAX_TRUE];
    __shared__ float sT[MAX_TRUE];
    int bid = blockIdx.x;
    int s, local, lnb, Sdim, objofs, spb;
    const float* fm;
    if (bid < 144)      { s = 0; local = bid;       lnb = 3;  Sdim = 19; objofs = 0;     spb = 1083;  fm = fm0; }
    else if (bid < 720) { s = 1; local = bid - 144; lnb = 12; Sdim = 38; objofs = 17328; spb = 4332;  fm = fm1; }
    else                { s = 2; local = bid - 720; lnb = 46; Sdim = 76; objofs = 86640; spb = 17328; fm = fm2; }
    int ba = local / lnb;
    int chunk = local - ba * lnb;
    int a = ba % 3, b = ba / 3;
    int slot = s * 16 + b;
    int tid = threadIdx.x;  // 128
    sA[tid] = boxesA[slot * MAX_TRUE + tid];
    sT[tid] = boxesT[slot * MAX_TRUE + tid];
    __syncthreads();
    int kr = (counts[slot] + 3) & ~3;
    int HW = Sdim * Sdim;
    int hw = chunk * 128 + tid;
    float lconf = 0.f;
    if (hw < HW) {
        int ob = objmask[objofs + b * spb + hw * 3 + a];
        const float* f = fm + ((size_t)(b * 255 + a * 85)) * HW + hw;
        float l0 = f[0], l1 = f[(size_t)HW], l2 = f[2 * (size_t)HW],
              l3 = f[3 * (size_t)HW], l4 = f[4 * (size_t)HW];
        if (!ob) {
            int h = hw / Sdim, w = hw - h * Sdim;
            float aw = d_anch[s][a][0], ah = d_anch[s][a][1];
            const float inv_in = 1.0f / 608.0f;
            float px = (sigmoidf_(l0) + (float)w) / (float)Sdim;
            float py = (sigmoidf_(l1) + (float)h) / (float)Sdim;
            float pw = aw * expf(l2) * inv_in;
            float ph = ah * expf(l3) * inv_in;
            float pminx = px - 0.5f * pw, pmaxx = px + 0.5f * pw;
            float pminy = py - 0.5f * ph, pmaxy = py + 0.5f * ph;
            float pa = pw * ph;
            // best_iou < 0.5  <=>  max_i(3*inter_i - ta_i) < pa
            float m0 = 0.f, m1 = 0.f, m2 = 0.f, m3 = 0.f;
            for (int i = 0; i < kr; i += 4) {
                float4 b0 = sA[i], b1 = sA[i + 1], b2 = sA[i + 2], b3 = sA[i + 3];
                float t0 = sT[i], t1 = sT[i + 1], t2 = sT[i + 2], t3 = sT[i + 3];
                float ix, iy;
                ix = fmaxf(fminf(pmaxx, b0.z) - fmaxf(pminx, b0.x), 0.f);
                iy = fmaxf(fminf(pmaxy, b0.w) - fmaxf(pminy, b0.y), 0.f);
                m0 = fmaxf(m0, fmaf(3.0f, ix * iy, -t0));
                ix = fmaxf(fminf(pmaxx, b1.z) - fmaxf(pminx, b1.x), 0.f);
                iy = fmaxf(fminf(pmaxy, b1.w) - fmaxf(pminy, b1.y), 0.f);
                m1 = fmaxf(m1, fmaf(3.0f, ix * iy, -t1));
                ix = fmaxf(fminf(pmaxx, b2.z) - fmaxf(pminx, b2.x), 0.f);
                iy = fmaxf(fminf(pmaxy, b2.w) - fmaxf(pminy, b2.y), 0.f);
                m2 = fmaxf(m2, fmaf(3.0f, ix * iy, -t2));
                ix = fmaxf(fminf(pmaxx, b3.z) - fmaxf(pminx, b3.x), 0.f);
                iy = fmaxf(fminf(pmaxy, b3.w) - fmaxf(pminy, b3.y), 0.f);
                m3 = fmaxf(m3, fmaf(3.0f, ix * iy, -t3));
            }
            float m = fmaxf(fmaxf(m0, m1), fmaxf(m2, m3));
            lconf = (m < pa) ? softplusf_(l4) : 0.f;
        }
    }
    // per-wave reduce; each wave writes its own partial (deterministic)
    int wid = tid >> 6;
    #pragma unroll
    for (int o = 32; o > 0; o >>= 1)
        lconf += __shfl_down(lconf, o);
    if ((tid & 63) == 0)
        partials[bid * 2 + wid] = lconf;
}

__global__ void finalize_kernel(const float* __restrict__ partials, int n,
                                const float* __restrict__ banks,
                                float* __restrict__ out) {
    __shared__ float red[4][4];
    int tid = threadIdx.x;  // 256
    float ssum = 0.f;
    for (int i = tid; i < n; i += 256) ssum += partials[i];
    float oxy = 0.f, owh = 0.f, oconf = 0.f, ocls = 0.f;
    if (tid < NBANK) {
        const float* bp = banks + tid * 16;
        oxy = bp[0]; owh = bp[1]; oconf = bp[2]; ocls = bp[3];
    }
    #pragma unroll
    for (int o = 32; o > 0; o >>= 1) {
        ssum += __shfl_down(ssum, o);
        oxy += __shfl_down(oxy, o);
        owh += __shfl_down(owh, o);
        oconf += __shfl_down(oconf, o);
        ocls += __shfl_down(ocls, o);
    }
    if ((tid & 63) == 0) {
        int w = tid >> 6;
        red[w][0] = ssum + oconf;  // conf partial + bank conf
        red[w][1] = oxy;
        red[w][2] = owh;
        red[w][3] = ocls;
    }
    __syncthreads();
    if (tid == 0) {
        float conf = 0.f, xy = 0.f, wh = 0.f, cls = 0.f;
        for (int i = 0; i < 4; ++i) {
            conf += red[i][0]; xy += red[i][1]; wh += red[i][2]; cls += red[i][3];
        }
        const float invB = 1.0f / 16.0f;
        float a0 = xy * invB;
        float a1 = wh * invB;
        float a2 = conf * invB;
        float a3 = cls * invB;
        out[1] = a0; out[2] = a1; out[3] = a2; out[4] = a3;
        out[0] = a0 + a1 + a2 + a3;
    }
}

extern "C" void kernel_launch(void* const* d_in, const int* in_sizes, int n_in,
                              void* d_out, int out_size, void* d_ws, size_t ws_size,
                              hipStream_t stream) {
    const float* fm0 = (const float*)d_in[0];
    const float* fm1 = (const float*)d_in[1];
    const float* fm2 = (const float*)d_in[2];
    const float* yt0 = (const float*)d_in[3];
    const float* yt1 = (const float*)d_in[4];
    const float* yt2 = (const float*)d_in[5];
    float* out = (float*)d_out;

    // workspace layout (bytes)
    char* ws = (char*)d_ws;
    int* cnt = (int*)ws;                                  // 192
    int* counts = (int*)(ws + 192);                       // 192
    float* banks = (float*)(ws + 448);                    // 128 * 64B = 8192
    float4* boxesA = (float4*)(ws + 8640);                // 48*128*16 = 98304
    float* boxesT = (float*)(ws + 106944);                // 48*128*4  = 24576
    float* cand = (float*)(ws + 131520);                  // 48*256*5*4 = 245760
    unsigned char* objmask = (unsigned char*)(ws + 377280); // 363888
    float* partials = (float*)(ws + 741168);              // 5856*4 = 23424

    // zero cnt + banks header (8640 B = 2160 words) with a tiny kernel:
    // the runtime's fillBufferAligned blit cost ~54 us/dispatch in-graph.
    zero_ws<<<1, 256, 0, stream>>>((float*)d_ws, 2160);

    cand_kernel<<<1422, 256, 0, stream>>>(yt0, yt1, yt2, objmask, cand, cnt);
    select_boxes<<<48, MAX_CAND, 0, stream>>>(cand, cnt, boxesA, boxesT, counts);
    obj_loss_kernel<<<dim3(MAX_CAND / 4, 48), 256, 0, stream>>>(fm0, fm1, fm2, yt0, yt1, yt2,
                                                                cand, cnt, banks);
    conf_kernel<<<2928, 128, 0, stream>>>(fm0, fm1, fm2, objmask,
                                          boxesA, boxesT, counts, partials);
    finalize_kernel<<<1, 256, 0, stream>>>(partials, 5856, banks, out);
}